// Round 1
// 1516.606 us; speedup vs baseline: 1.0148x; 1.0148x over previous
//
#include <hip/hip_runtime.h>

// ---------------- problem constants ----------------
#define NNODES 8192
#define NEDGES 262144
#define CCH    128          // sphere channels (C = EC = 128)
#define HCH    512          // hidden channels
#define GCOLS  6144         // 2*2560 (eq gates) + 2*512 (ne gates)
#define ROWS   204800       // N * M = 8192 * 25
#define XSPAD  136          // gate-gemm LDS row stride (bf16 elems)
#define HGPAD  72           // hg LDS row stride

typedef __bf16 bf16_t;
typedef __bf16 bf16x8 __attribute__((ext_vector_type(8)));
typedef __bf16 bf16x4 __attribute__((ext_vector_type(4)));
typedef float  f32x4  __attribute__((ext_vector_type(4)));

__device__ __forceinline__ float siluf(float x) { return x / (1.f + __expf(-x)); }

// ---------------- workspace layout (bytes) ----------------
constexpr size_t OFF_CSUM  = 0;           // 8192*128 f32   = 4,194,304 (mean, router input)
constexpr size_t OFF_DEG   = 4194304;     // 8192 i32
constexpr size_t OFF_OFFS  = 4227072;     // 8193 i32 (padded)
constexpr size_t OFF_CUR   = 4263936;     // 8192 i32
constexpr size_t OFF_EIDS  = 4296704;     // 262144 i32
constexpr size_t OFF_WRT   = 5345280;     // 8192*4 f32
constexpr size_t OFF_CBF   = 5476352;     // 8192*128 bf16
constexpr size_t OFF_WPT   = 7573504;     // 6144*128 bf16
constexpr size_t OFF_BPK   = 9146368;     // 6144 f32
constexpr size_t OFF_W1T   = 9170944;     // 4*512*128 bf16
constexpr size_t OFF_W2T   = 9695232;     // 4*128*512 bf16
constexpr size_t OFF_GATES = 10219520;    // chunk*6144 bf16 (adaptive)

// ---------------- kernel 1a: per-node degree count ----------------
__global__ __launch_bounds__(256) void edge_count_kernel(
    const int* __restrict__ edge_index, int* __restrict__ deg)
{
  int e = blockIdx.x * 256 + threadIdx.x;
  atomicAdd(&deg[edge_index[NEDGES + e]], 1);
}

// ---------------- kernel 1b: exclusive scan (single block) ----------------
__global__ __launch_bounds__(256) void scan_kernel(
    const int* __restrict__ deg, int* __restrict__ offs, int* __restrict__ cur)
{
  __shared__ int part[256];
  int t = threadIdx.x;
  int s = 0;
  #pragma unroll 4
  for (int i = 0; i < 32; ++i) s += deg[t * 32 + i];
  part[t] = s;
  __syncthreads();
  int incl = s;
  for (int off = 1; off < 256; off <<= 1) {
    int u = (t >= off) ? part[t - off] : 0;
    __syncthreads();
    incl += u;
    part[t] = incl;
    __syncthreads();
  }
  int run = incl - s;      // exclusive prefix of this thread's 32-chunk
  for (int i = 0; i < 32; ++i) {
    int d = deg[t * 32 + i];
    offs[t * 32 + i] = run;
    cur[t * 32 + i]  = run;
    run += d;
  }
  if (t == 255) offs[8192] = run;   // == NEDGES
}

// ---------------- kernel 1c: fill CSR edge-id slots ----------------
__global__ __launch_bounds__(256) void edge_fill_kernel(
    const int* __restrict__ edge_index, int* __restrict__ cur, int* __restrict__ eids)
{
  int e = blockIdx.x * 256 + threadIdx.x;
  int dst = edge_index[NEDGES + e];
  int pos = atomicAdd(&cur[dst], 1);
  eids[pos] = e;
}

// ---------------- kernel 1d: gather + mean (fuses old mean kernel) ----------------
__global__ __launch_bounds__(128) void gather_mean_kernel(
    const float* __restrict__ t_ij, const int* __restrict__ offs,
    const int* __restrict__ eids, float* __restrict__ csum, bf16_t* __restrict__ cbf)
{
  int n = blockIdx.x, tid = threadIdx.x;
  int o0 = offs[n], o1 = offs[n + 1];
  float a0 = 0.f, a1 = 0.f;
  int j = o0;
  for (; j + 1 < o1; j += 2) {
    int e0 = eids[j], e1 = eids[j + 1];
    a0 += t_ij[(size_t)e0 * CCH + tid];
    a1 += t_ij[(size_t)e1 * CCH + tid];
  }
  if (j < o1) a0 += t_ij[(size_t)eids[j] * CCH + tid];
  float m = (a0 + a1) / fmaxf((float)(o1 - o0), 1.f);
  csum[(size_t)n * CCH + tid] = m;      // fp32 mean for router
  cbf[(size_t)n * CCH + tid]  = (bf16_t)m;
}

// ---------------- kernel 3: pack/transpose weights (fp32 -> bf16) ----------------
__global__ __launch_bounds__(256) void pack_kernel(
    const float* __restrict__ eq_gate_w, const float* __restrict__ ne_gate_w,
    const float* __restrict__ eq_gate_b, const float* __restrict__ ne_gate_b,
    const float* __restrict__ eq_w1, const float* __restrict__ ne_w1,
    const float* __restrict__ eq_w2, const float* __restrict__ ne_w2,
    bf16_t* __restrict__ WpackT, float* __restrict__ bpack,
    bf16_t* __restrict__ w1T, bf16_t* __restrict__ w2T)
{
  int idx = blockIdx.x * 256 + threadIdx.x;        // 1,316,864 total
  if (idx < 786432) {                              // WpackT[j][c] = Wpack[c][j]
    int j = idx >> 7, c = idx & 127;
    float v;
    if (j < 5120) { int e = j / 2560, h = j - e * 2560;
      v = eq_gate_w[(size_t)e * 327680 + (size_t)c * 2560 + h]; }
    else { int j2 = j - 5120; int e = j2 >> 9, h = j2 & 511;
      v = ne_gate_w[(size_t)e * 65536 + (size_t)c * 512 + h]; }
    WpackT[idx] = (bf16_t)v;
  } else if (idx < 792576) {                       // bpack (f32)
    int j = idx - 786432;
    float v;
    if (j < 5120) { int e = j / 2560; v = eq_gate_b[e * 2560 + (j - e * 2560)]; }
    else { int j2 = j - 5120; int e = j2 >> 9; v = ne_gate_b[e * 512 + (j2 & 511)]; }
    bpack[j] = v;
  } else if (idx < 1054720) {                      // w1T[e][h][c] = w1[e][c][h]
    int i = idx - 792576;
    int e = i >> 16, rest = i & 65535, h = rest >> 7, c = rest & 127;
    float v = (e < 2) ? eq_w1[(size_t)e * 65536 + (size_t)c * 512 + h]
                      : ne_w1[(size_t)(e - 2) * 65536 + (size_t)c * 512 + h];
    w1T[i] = (bf16_t)v;
  } else if (idx < 1316864) {                      // w2T[e][c][h] = w2[e][h][c]
    int i = idx - 1054720;
    int e = i >> 16, rest = i & 65535, c = rest >> 9, h = rest & 511;
    float v = (e < 2) ? eq_w2[(size_t)e * 65536 + (size_t)h * 128 + c]
                      : ne_w2[(size_t)(e - 2) * 65536 + (size_t)h * 128 + c];
    w2T[i] = (bf16_t)v;
  }
}

// ---------------- kernel 4: router (all fp32) ----------------
__global__ __launch_bounds__(128) void router_kernel(
    const float* __restrict__ c,
    const float* __restrict__ r_w1, const float* __restrict__ r_b1,
    const float* __restrict__ r_w2, const float* __restrict__ r_b2,
    float* __restrict__ wroute)
{
  __shared__ float cl[128];
  __shared__ float h1[128];
  __shared__ float lg[4];
  int n = blockIdx.x, tid = threadIdx.x;
  cl[tid] = c[(size_t)n * 128 + tid];
  __syncthreads();
  float a = 0.f;
  #pragma unroll 8
  for (int k = 0; k < 128; ++k) a += cl[k] * r_w1[k * 128 + tid];
  a += r_b1[tid];
  h1[tid] = siluf(a);
  __syncthreads();
  if (tid < 4) {
    float s = 0.f;
    for (int j = 0; j < 128; ++j) s += h1[j] * r_w2[j * 4 + tid];
    lg[tid] = s + r_b2[tid];
  }
  __syncthreads();
  if (tid == 0) {
    float m = fmaxf(fmaxf(lg[0], lg[1]), fmaxf(lg[2], lg[3]));
    float e0 = __expf(lg[0] - m), e1 = __expf(lg[1] - m);
    float e2 = __expf(lg[2] - m), e3 = __expf(lg[3] - m);
    float s = 1.f / (e0 + e1 + e2 + e3);
    f32x4 w = {e0 * s, e1 * s, e2 * s, e3 * s};
    *(f32x4*)&wroute[n * 4] = w;
  }
}

// ---------------- kernel 5: gate GEMM  gates[n][j] = silu(c@Wpack + b) ----------------
__global__ __launch_bounds__(256, 2) void gate_gemm_kernel(
    const bf16_t* __restrict__ WpackT, const bf16_t* __restrict__ cbf,
    const float* __restrict__ bpack, bf16_t* __restrict__ gates, int n0)
{
  __shared__ bf16_t gt[128 * XSPAD];
  int jt = blockIdx.x, nt = blockIdx.y;
  int tid = threadIdx.x;
  int wave = tid >> 6, lane = tid & 63;
  int wr = wave >> 1, wc = wave & 1;
  int l15 = lane & 15, quad = lane >> 4;

  f32x4 acc[4][4];
  #pragma unroll
  for (int i = 0; i < 4; ++i)
    #pragma unroll
    for (int j = 0; j < 4; ++j) acc[i][j] = {0.f, 0.f, 0.f, 0.f};

  const bf16_t* abase = WpackT + ((size_t)jt * 128 + wr * 64 + l15) * 128 + quad * 8;
  const bf16_t* bbase = cbf + ((size_t)(n0 + nt * 128) + wc * 64 + l15) * 128 + quad * 8;
  #pragma unroll
  for (int ks = 0; ks < 4; ++ks) {
    bf16x8 af[4], bfr[4];
    #pragma unroll
    for (int tr = 0; tr < 4; ++tr) af[tr] = *(const bf16x8*)(abase + (size_t)tr * 16 * 128 + ks * 32);
    #pragma unroll
    for (int tc = 0; tc < 4; ++tc) bfr[tc] = *(const bf16x8*)(bbase + (size_t)tc * 16 * 128 + ks * 32);
    #pragma unroll
    for (int tr = 0; tr < 4; ++tr)
      #pragma unroll
      for (int tc = 0; tc < 4; ++tc)
        acc[tr][tc] = __builtin_amdgcn_mfma_f32_16x16x32_bf16(af[tr], bfr[tc], acc[tr][tc], 0, 0, 0);
  }
  #pragma unroll
  for (int tr = 0; tr < 4; ++tr) {
    int j0 = wr * 64 + tr * 16 + quad * 4;
    f32x4 bb = *(const f32x4*)&bpack[jt * 128 + j0];
    #pragma unroll
    for (int tc = 0; tc < 4; ++tc) {
      int nl = wc * 64 + tc * 16 + l15;
      f32x4 v = acc[tr][tc];
      bf16x4 gv;
      #pragma unroll
      for (int q = 0; q < 4; ++q) gv[q] = (bf16_t)siluf(v[q] + bb[q]);
      *(bf16x4*)&gt[nl * XSPAD + j0] = gv;
    }
  }
  __syncthreads();
  #pragma unroll
  for (int it = 0; it < 8; ++it) {
    int idx = it * 2048 + tid * 8;
    int lr = idx >> 7, col = idx & 127;
    *(bf16x8*)&gates[((size_t)nt * 128 + lr) * GCOLS + jt * 128 + col] =
        *(const bf16x8*)&gt[lr * XSPAD + col];
  }
}

// ---------------- kernel 6: fused experts (barrier-free, wave-private) ----------------
// Each wave owns 32 rows of (n,m) space end-to-end:
//   GEMM1 D1[h(4x16)][r(2x16)] = w1T * x(regs), K=128
//   gate  -> private hg slice [32][HGPAD] bf16 (intra-wave only; DS pipe is
//            in-order per wave, so no __syncthreads needed)
//   GEMM2 oacc[c(8x16)][r(2x16)] += w2T * hg, K=64
// x panel (32 rows x 128 K) lives in 32 VGPRs/lane; no xs LDS at all.
__global__ __launch_bounds__(256, 3) void fused_experts_kernel(
    const float* __restrict__ x,       // [204800][128] fp32
    const bf16_t* __restrict__ w1T,    // [4][512][128]
    const bf16_t* __restrict__ w2T,    // [4][128][512]
    const bf16_t* __restrict__ gates,  // [chunk][6144] (node n at row n-n0)
    const float* __restrict__ wroute,  // [8192][4]
    const float* __restrict__ ne_b1,   // [2][512] fp32
    const float* __restrict__ ne_b2,   // [2][128] fp32
    float* __restrict__ out,           // [204800][128] fp32
    int n0)
{
  __shared__ bf16_t hg[4 * 32 * HGPAD];   // 18,432 B total, wave-private slices

  const int tid = threadIdx.x;
  const int wave = tid >> 6, lane = tid & 63;
  const int l15 = lane & 15, quad = lane >> 4;
  const int r0 = n0 * 25 + blockIdx.x * 128;
  const int rbase = wave * 32;
  bf16_t* hgw = hg + wave * 32 * HGPAD;

  // per-lane row metadata + x panel into registers
  int nloc[2], lidx[2];
  f32x4 rw[2];
  bf16x8 xf[2][4];
  #pragma unroll
  for (int tc = 0; tc < 2; ++tc) {
    int r = r0 + rbase + tc * 16 + l15;
    int n = r / 25;
    int m = r - n * 25;
    nloc[tc] = n - n0;
    lidx[tc] = (m == 0) ? 0 : (m < 4) ? 1 : (m < 9) ? 2 : (m < 16) ? 3 : 4;
    rw[tc] = *(const f32x4*)&wroute[n * 4];
    const float* xr = x + (size_t)r * CCH + quad * 8;
    #pragma unroll
    for (int ks = 0; ks < 4; ++ks) {
      f32x4 a = *(const f32x4*)(xr + ks * 32);
      f32x4 b = *(const f32x4*)(xr + ks * 32 + 4);
      bf16x8 v;
      #pragma unroll
      for (int q = 0; q < 4; ++q) { v[q] = (bf16_t)a[q]; v[4 + q] = (bf16_t)b[q]; }
      xf[tc][ks] = v;
    }
  }

  f32x4 oacc[8][2];
  #pragma unroll
  for (int i = 0; i < 8; ++i)
    #pragma unroll
    for (int j = 0; j < 2; ++j) oacc[i][j] = {0.f, 0.f, 0.f, 0.f};

  #pragma unroll 1
  for (int e = 0; e < 4; ++e) {
    const bool is_eq = (e < 2);
    #pragma unroll 1
    for (int hc = 0; hc < 8; ++hc) {
      // ---- GEMM1: hacc[h(4x16)][r(2x16)], K=128 ----
      f32x4 hacc[4][2];
      #pragma unroll
      for (int i = 0; i < 4; ++i)
        #pragma unroll
        for (int j = 0; j < 2; ++j) hacc[i][j] = {0.f, 0.f, 0.f, 0.f};
      const bf16_t* a1 = w1T + ((size_t)(e * 512 + hc * 64 + l15)) * CCH + quad * 8;
      #pragma unroll
      for (int ks = 0; ks < 4; ++ks) {
        bf16x8 af[4];
        #pragma unroll
        for (int tr = 0; tr < 4; ++tr)
          af[tr] = *(const bf16x8*)(a1 + (size_t)tr * 16 * CCH + ks * 32);
        #pragma unroll
        for (int tr = 0; tr < 4; ++tr)
          #pragma unroll
          for (int tc = 0; tc < 2; ++tc)
            hacc[tr][tc] = __builtin_amdgcn_mfma_f32_16x16x32_bf16(af[tr], xf[tc][ks], hacc[tr][tc], 0, 0, 0);
      }
      // ---- gating + hg write (own slice only) ----
      #pragma unroll
      for (int tc = 0; tc < 2; ++tc) {
        float wre = rw[tc][e];
        size_t gbase = (size_t)nloc[tc] * GCOLS + hc * 64
                     + (is_eq ? (size_t)(e * 2560 + lidx[tc] * 512)
                              : (size_t)(5120 + (e - 2) * 512));
        #pragma unroll
        for (int tr = 0; tr < 4; ++tr) {
          int hl = tr * 16 + quad * 4;
          f32x4 v = hacc[tr][tc];
          bf16x4 gv = *(const bf16x4*)&gates[gbase + hl];
          if (is_eq) {
            if (lidx[tc] == 0) {
              #pragma unroll
              for (int q = 0; q < 4; ++q) v[q] = siluf(v[q]);
            }
          } else {
            f32x4 b1 = *(const f32x4*)&ne_b1[(e - 2) * 512 + hc * 64 + hl];
            #pragma unroll
            for (int q = 0; q < 4; ++q) v[q] = siluf(v[q] + b1[q]);
          }
          bf16x4 hv;
          #pragma unroll
          for (int q = 0; q < 4; ++q) hv[q] = (bf16_t)(v[q] * (float)gv[q] * wre);
          *(bf16x4*)&hgw[(tc * 16 + l15) * HGPAD + hl] = hv;
        }
      }
      // pin order: writes above, reads below (DS pipe is in-order per wave;
      // wave_barrier is a zero-cost compiler fence, no s_barrier emitted)
      __builtin_amdgcn_wave_barrier();
      // ---- GEMM2: oacc[c(8x16)][r(2x16)] += w2T(chunk) * hg, K=64 ----
      const bf16_t* a2 = w2T + ((size_t)(e * 128 + l15)) * HCH + hc * 64 + quad * 8;
      #pragma unroll
      for (int ks = 0; ks < 2; ++ks) {
        bf16x8 bfr[2];
        #pragma unroll
        for (int tc = 0; tc < 2; ++tc)
          bfr[tc] = *(const bf16x8*)&hgw[(tc * 16 + l15) * HGPAD + ks * 32 + quad * 8];
        #pragma unroll
        for (int tr = 0; tr < 8; ++tr) {
          bf16x8 af2 = *(const bf16x8*)(a2 + (size_t)tr * 16 * HCH + ks * 32);
          #pragma unroll
          for (int tc = 0; tc < 2; ++tc)
            oacc[tr][tc] = __builtin_amdgcn_mfma_f32_16x16x32_bf16(af2, bfr[tc], oacc[tr][tc], 0, 0, 0);
        }
      }
      __builtin_amdgcn_wave_barrier();   // keep next-iter hg writes after these reads
    }
  }
  // ---- epilogue: out[r][c] = oacc + w_ne*b2 terms (fp32 store) ----
  #pragma unroll
  for (int tc = 0; tc < 2; ++tc) {
    size_t rg = (size_t)(r0 + rbase + tc * 16 + l15);
    float wn0 = rw[tc][2], wn1 = rw[tc][3];
    #pragma unroll
    for (int tr = 0; tr < 8; ++tr) {
      int c0 = tr * 16 + quad * 4;
      f32x4 v = oacc[tr][tc];
      f32x4 b20 = *(const f32x4*)&ne_b2[c0];
      f32x4 b21 = *(const f32x4*)&ne_b2[128 + c0];
      f32x4 ov;
      #pragma unroll
      for (int q = 0; q < 4; ++q)
        ov[q] = v[q] + wn0 * b20[q] + wn1 * b21[q];
      *(f32x4*)&out[rg * CCH + c0] = ov;
    }
  }
}

// ---------------- launch ----------------
extern "C" void kernel_launch(void* const* d_in, const int* in_sizes, int n_in,
                              void* d_out, int out_size, void* d_ws, size_t ws_size,
                              hipStream_t stream)
{
  const float* x_emb     = (const float*)d_in[0];
  const float* t_ij      = (const float*)d_in[1];
  const int*   edge_index= (const int*)d_in[2];
  const float* eq_w1     = (const float*)d_in[3];
  const float* eq_gate_w = (const float*)d_in[4];
  const float* eq_gate_b = (const float*)d_in[5];
  const float* eq_w2     = (const float*)d_in[6];
  const float* ne_w1     = (const float*)d_in[7];
  const float* ne_b1     = (const float*)d_in[8];
  const float* ne_gate_w = (const float*)d_in[9];
  const float* ne_gate_b = (const float*)d_in[10];
  const float* ne_w2     = (const float*)d_in[11];
  const float* ne_b2     = (const float*)d_in[12];
  const float* r_w1      = (const float*)d_in[13];
  const float* r_b1      = (const float*)d_in[14];
  const float* r_w2      = (const float*)d_in[15];
  const float* r_b2      = (const float*)d_in[16];
  float* out = (float*)d_out;

  char* ws = (char*)d_ws;
  float*  csum   = (float*)(ws + OFF_CSUM);
  int*    deg    = (int*)(ws + OFF_DEG);
  int*    offs   = (int*)(ws + OFF_OFFS);
  int*    cur    = (int*)(ws + OFF_CUR);
  int*    eids   = (int*)(ws + OFF_EIDS);
  float*  wroute = (float*)(ws + OFF_WRT);
  bf16_t* cbf    = (bf16_t*)(ws + OFF_CBF);
  bf16_t* WpackT = (bf16_t*)(ws + OFF_WPT);
  float*  bpack  = (float*)(ws + OFF_BPK);
  bf16_t* w1T    = (bf16_t*)(ws + OFF_W1T);
  bf16_t* w2T    = (bf16_t*)(ws + OFF_W2T);
  bf16_t* gates  = (bf16_t*)(ws + OFF_GATES);

  // Adaptive node-chunking for the gates buffer (ws_size constant across calls).
  size_t avail = (ws_size > OFF_GATES) ? ws_size - OFF_GATES : 0;
  int chunk = 128;
  for (int c = NNODES; c >= 128; c >>= 1) {
    if ((size_t)c * GCOLS * sizeof(bf16_t) <= avail) { chunk = c; break; }
  }

  hipMemsetAsync(ws + OFF_DEG, 0, 32768, stream);   // zero deg only

  // CSR build + gather-mean (replaces 33.5M-atomic scatter + mean kernels)
  edge_count_kernel<<<NEDGES / 256, 256, 0, stream>>>(edge_index, deg);
  scan_kernel<<<1, 256, 0, stream>>>(deg, offs, cur);
  edge_fill_kernel<<<NEDGES / 256, 256, 0, stream>>>(edge_index, cur, eids);
  gather_mean_kernel<<<NNODES, 128, 0, stream>>>(t_ij, offs, eids, csum, cbf);

  pack_kernel<<<5144, 256, 0, stream>>>(eq_gate_w, ne_gate_w, eq_gate_b, ne_gate_b,
                                        eq_w1, ne_w1, eq_w2, ne_w2,
                                        WpackT, bpack, w1T, w2T);
  router_kernel<<<NNODES, 128, 0, stream>>>(csum, r_w1, r_b1, r_w2, r_b2, wroute);

  for (int n0 = 0; n0 < NNODES; n0 += chunk) {
    gate_gemm_kernel<<<dim3(GCOLS / 128, chunk / 128), 256, 0, stream>>>(
        WpackT, cbf, bpack, gates, n0);
    fused_experts_kernel<<<chunk * 25 / 128, 256, 0, stream>>>(
        x_emb, w1T, w2T, gates, wroute, ne_b1, ne_b2, out, n0);
  }
}

// Round 2
// 894.633 us; speedup vs baseline: 1.7203x; 1.6952x over previous
//
#include <hip/hip_runtime.h>

// ---------------- problem constants ----------------
#define NNODES 8192
#define NEDGES 262144
#define CCH    128          // sphere channels (C = EC = 128)
#define HCH    512          // hidden channels
#define GCOLS  6144         // 2*2560 (eq gates) + 2*512 (ne gates)
#define ROWS   204800       // N * M = 8192 * 25
#define XSPAD  136          // gate-gemm LDS row stride (bf16 elems)
#define HGPAD  72           // hg LDS row stride

typedef __bf16 bf16_t;
typedef __bf16 bf16x8 __attribute__((ext_vector_type(8)));
typedef __bf16 bf16x4 __attribute__((ext_vector_type(4)));
typedef float  f32x4  __attribute__((ext_vector_type(4)));

__device__ __forceinline__ float siluf(float x) { return x / (1.f + __expf(-x)); }

#define GLOAD_LDS(g, l) __builtin_amdgcn_global_load_lds( \
    (const __attribute__((address_space(1))) void*)(g), \
    (__attribute__((address_space(3))) void*)(l), 16, 0, 0)

// ---------------- workspace layout (bytes) ----------------
constexpr size_t OFF_CSUM  = 0;           // 8192*128 f32 (mean, router input)
constexpr size_t OFF_DEG   = 4194304;     // 8192 i32
constexpr size_t OFF_OFFS  = 4227072;     // 8193 i32 (padded)
constexpr size_t OFF_CUR   = 4263936;     // 8192 i32
constexpr size_t OFF_EIDS  = 4296704;     // 262144 i32
constexpr size_t OFF_WRT   = 5345280;     // 8192*4 f32
constexpr size_t OFF_CBF   = 5476352;     // 8192*128 bf16
constexpr size_t OFF_WPT   = 7573504;     // 6144*128 bf16
constexpr size_t OFF_BPK   = 9146368;     // 6144 f32
constexpr size_t OFF_W1T   = 9170944;     // 4*512*128 bf16 ((e,hc)-chunked rows)
constexpr size_t OFF_W2T   = 9695232;     // 4*8*128*64 bf16 ((e,hc)-chunked)
constexpr size_t OFF_GATES = 10219520;    // chunk*6144 bf16 (adaptive)

// ---------------- kernel 1a: per-node degree count ----------------
__global__ __launch_bounds__(256) void edge_count_kernel(
    const int* __restrict__ edge_index, int* __restrict__ deg)
{
  int e = blockIdx.x * 256 + threadIdx.x;
  atomicAdd(&deg[edge_index[NEDGES + e]], 1);
}

// ---------------- kernel 1b: exclusive scan (single block) ----------------
__global__ __launch_bounds__(256) void scan_kernel(
    const int* __restrict__ deg, int* __restrict__ offs, int* __restrict__ cur)
{
  __shared__ int part[256];
  int t = threadIdx.x;
  int s = 0;
  #pragma unroll 4
  for (int i = 0; i < 32; ++i) s += deg[t * 32 + i];
  part[t] = s;
  __syncthreads();
  int incl = s;
  for (int off = 1; off < 256; off <<= 1) {
    int u = (t >= off) ? part[t - off] : 0;
    __syncthreads();
    incl += u;
    part[t] = incl;
    __syncthreads();
  }
  int run = incl - s;      // exclusive prefix of this thread's 32-chunk
  for (int i = 0; i < 32; ++i) {
    int d = deg[t * 32 + i];
    offs[t * 32 + i] = run;
    cur[t * 32 + i]  = run;
    run += d;
  }
  if (t == 255) offs[8192] = run;   // == NEDGES
}

// ---------------- kernel 1c: fill CSR edge-id slots ----------------
__global__ __launch_bounds__(256) void edge_fill_kernel(
    const int* __restrict__ edge_index, int* __restrict__ cur, int* __restrict__ eids)
{
  int e = blockIdx.x * 256 + threadIdx.x;
  int dst = edge_index[NEDGES + e];
  int pos = atomicAdd(&cur[dst], 1);
  eids[pos] = e;
}

// ---------------- kernel 1d: gather + mean ----------------
__global__ __launch_bounds__(128) void gather_mean_kernel(
    const float* __restrict__ t_ij, const int* __restrict__ offs,
    const int* __restrict__ eids, float* __restrict__ csum, bf16_t* __restrict__ cbf)
{
  int n = blockIdx.x, tid = threadIdx.x;
  int o0 = offs[n], o1 = offs[n + 1];
  float a0 = 0.f, a1 = 0.f;
  int j = o0;
  for (; j + 1 < o1; j += 2) {
    int e0 = eids[j], e1 = eids[j + 1];
    a0 += t_ij[(size_t)e0 * CCH + tid];
    a1 += t_ij[(size_t)e1 * CCH + tid];
  }
  if (j < o1) a0 += t_ij[(size_t)eids[j] * CCH + tid];
  float m = (a0 + a1) / fmaxf((float)(o1 - o0), 1.f);
  csum[(size_t)n * CCH + tid] = m;
  cbf[(size_t)n * CCH + tid]  = (bf16_t)m;
}

// ---------------- kernel 3: pack/transpose weights (fp32 -> bf16) ----------------
__global__ __launch_bounds__(256) void pack_kernel(
    const float* __restrict__ eq_gate_w, const float* __restrict__ ne_gate_w,
    const float* __restrict__ eq_gate_b, const float* __restrict__ ne_gate_b,
    const float* __restrict__ eq_w1, const float* __restrict__ ne_w1,
    const float* __restrict__ eq_w2, const float* __restrict__ ne_w2,
    bf16_t* __restrict__ WpackT, float* __restrict__ bpack,
    bf16_t* __restrict__ w1T, bf16_t* __restrict__ w2c)
{
  int idx = blockIdx.x * 256 + threadIdx.x;        // 1,316,864 total
  if (idx < 786432) {                              // WpackT[j][c] = Wpack[c][j]
    int j = idx >> 7, c = idx & 127;
    float v;
    if (j < 5120) { int e = j / 2560, h = j - e * 2560;
      v = eq_gate_w[(size_t)e * 327680 + (size_t)c * 2560 + h]; }
    else { int j2 = j - 5120; int e = j2 >> 9, h = j2 & 511;
      v = ne_gate_w[(size_t)e * 65536 + (size_t)c * 512 + h]; }
    WpackT[idx] = (bf16_t)v;
  } else if (idx < 792576) {                       // bpack (f32)
    int j = idx - 786432;
    float v;
    if (j < 5120) { int e = j / 2560; v = eq_gate_b[e * 2560 + (j - e * 2560)]; }
    else { int j2 = j - 5120; int e = j2 >> 9; v = ne_gate_b[e * 512 + (j2 & 511)]; }
    bpack[j] = v;
  } else if (idx < 1054720) {                      // w1T[e][h][c] = w1[e][c][h]
    int i = idx - 792576;
    int e = i >> 16, rest = i & 65535, h = rest >> 7, c = rest & 127;
    float v = (e < 2) ? eq_w1[(size_t)e * 65536 + (size_t)c * 512 + h]
                      : ne_w1[(size_t)(e - 2) * 65536 + (size_t)c * 512 + h];
    w1T[i] = (bf16_t)v;
  } else if (idx < 1316864) {                      // w2c[e][hc][c][h64] = w2[e][hc*64+h64][c]
    int i = idx - 1054720;
    int e = i >> 16, rest = i & 65535;
    int hc = rest >> 13, r2 = rest & 8191;
    int c = r2 >> 6, h64 = r2 & 63;
    int h = hc * 64 + h64;
    float v = (e < 2) ? eq_w2[(size_t)e * 65536 + (size_t)h * 128 + c]
                      : ne_w2[(size_t)(e - 2) * 65536 + (size_t)h * 128 + c];
    w2c[i] = (bf16_t)v;
  }
}

// ---------------- kernel 4: router (all fp32) ----------------
__global__ __launch_bounds__(128) void router_kernel(
    const float* __restrict__ c,
    const float* __restrict__ r_w1, const float* __restrict__ r_b1,
    const float* __restrict__ r_w2, const float* __restrict__ r_b2,
    float* __restrict__ wroute)
{
  __shared__ float cl[128];
  __shared__ float h1[128];
  __shared__ float lg[4];
  int n = blockIdx.x, tid = threadIdx.x;
  cl[tid] = c[(size_t)n * 128 + tid];
  __syncthreads();
  float a = 0.f;
  #pragma unroll 8
  for (int k = 0; k < 128; ++k) a += cl[k] * r_w1[k * 128 + tid];
  a += r_b1[tid];
  h1[tid] = siluf(a);
  __syncthreads();
  if (tid < 4) {
    float s = 0.f;
    for (int j = 0; j < 128; ++j) s += h1[j] * r_w2[j * 4 + tid];
    lg[tid] = s + r_b2[tid];
  }
  __syncthreads();
  if (tid == 0) {
    float m = fmaxf(fmaxf(lg[0], lg[1]), fmaxf(lg[2], lg[3]));
    float e0 = __expf(lg[0] - m), e1 = __expf(lg[1] - m);
    float e2 = __expf(lg[2] - m), e3 = __expf(lg[3] - m);
    float s = 1.f / (e0 + e1 + e2 + e3);
    f32x4 w = {e0 * s, e1 * s, e2 * s, e3 * s};
    *(f32x4*)&wroute[n * 4] = w;
  }
}

// ---------------- kernel 5: gate GEMM  gates[n][j] = silu(c@Wpack + b) ----------------
__global__ __launch_bounds__(256, 2) void gate_gemm_kernel(
    const bf16_t* __restrict__ WpackT, const bf16_t* __restrict__ cbf,
    const float* __restrict__ bpack, bf16_t* __restrict__ gates, int n0)
{
  __shared__ bf16_t gt[128 * XSPAD];
  int jt = blockIdx.x, nt = blockIdx.y;
  int tid = threadIdx.x;
  int wave = tid >> 6, lane = tid & 63;
  int wr = wave >> 1, wc = wave & 1;
  int l15 = lane & 15, quad = lane >> 4;

  f32x4 acc[4][4];
  #pragma unroll
  for (int i = 0; i < 4; ++i)
    #pragma unroll
    for (int j = 0; j < 4; ++j) acc[i][j] = {0.f, 0.f, 0.f, 0.f};

  const bf16_t* abase = WpackT + ((size_t)jt * 128 + wr * 64 + l15) * 128 + quad * 8;
  const bf16_t* bbase = cbf + ((size_t)(n0 + nt * 128) + wc * 64 + l15) * 128 + quad * 8;
  #pragma unroll
  for (int ks = 0; ks < 4; ++ks) {
    bf16x8 af[4], bfr[4];
    #pragma unroll
    for (int tr = 0; tr < 4; ++tr) af[tr] = *(const bf16x8*)(abase + (size_t)tr * 16 * 128 + ks * 32);
    #pragma unroll
    for (int tc = 0; tc < 4; ++tc) bfr[tc] = *(const bf16x8*)(bbase + (size_t)tc * 16 * 128 + ks * 32);
    #pragma unroll
    for (int tr = 0; tr < 4; ++tr)
      #pragma unroll
      for (int tc = 0; tc < 4; ++tc)
        acc[tr][tc] = __builtin_amdgcn_mfma_f32_16x16x32_bf16(af[tr], bfr[tc], acc[tr][tc], 0, 0, 0);
  }
  #pragma unroll
  for (int tr = 0; tr < 4; ++tr) {
    int j0 = wr * 64 + tr * 16 + quad * 4;
    f32x4 bb = *(const f32x4*)&bpack[jt * 128 + j0];
    #pragma unroll
    for (int tc = 0; tc < 4; ++tc) {
      int nl = wc * 64 + tc * 16 + l15;
      f32x4 v = acc[tr][tc];
      bf16x4 gv;
      #pragma unroll
      for (int q = 0; q < 4; ++q) gv[q] = (bf16_t)siluf(v[q] + bb[q]);
      *(bf16x4*)&gt[nl * XSPAD + j0] = gv;
    }
  }
  __syncthreads();
  #pragma unroll
  for (int it = 0; it < 8; ++it) {
    int idx = it * 2048 + tid * 8;
    int lr = idx >> 7, col = idx & 127;
    *(bf16x8*)&gates[((size_t)nt * 128 + lr) * GCOLS + jt * 128 + col] =
        *(const bf16x8*)&gt[lr * XSPAD + col];
  }
}

// ---------------- kernel 6: fused experts (LDS-staged weights) ----------------
// Wave-private 32-row structure kept (x panel in VGPRs = free B-operand).
// NEW: per-(e,hc) weight chunks (w1: 64h x 128k, w2: 128c x 64k, 16 KB each)
// staged into LDS via global_load_lds with pre-swizzled SOURCE addresses
// (byte ^= (row&7)<<4, rule #21: swizzle both sides or neither). A-fragments
// then come from LDS at ~2-way bank aliasing (free) instead of 128 KB/CU-iter
// of L2 fragment loads. Gates prefetched to regs before GEMM1 to hide L2 lat.
__global__ __launch_bounds__(256, 2) void fused_experts_kernel(
    const float* __restrict__ x,       // [204800][128] fp32
    const bf16_t* __restrict__ w1T,    // [4][512][128], (e,hc) chunk = 8192 elems
    const bf16_t* __restrict__ w2c,    // [4][8][128][64], (e,hc) chunk = 8192 elems
    const bf16_t* __restrict__ gates,  // [chunk][6144]
    const float* __restrict__ wroute,  // [8192][4]
    const float* __restrict__ ne_b1,   // [2][512] fp32
    const float* __restrict__ ne_b2,   // [2][128] fp32
    float* __restrict__ out,           // [204800][128] fp32
    int n0)
{
  __shared__ __align__(16) bf16_t ws1[8192];          // 16 KB w1 chunk (swizzled)
  __shared__ __align__(16) bf16_t ws2[8192];          // 16 KB w2 chunk (swizzled)
  __shared__ __align__(16) bf16_t hg[4 * 32 * HGPAD]; // 18 KB wave-private

  const int tid = threadIdx.x;
  const int wave = tid >> 6, lane = tid & 63;
  const int l15 = lane & 15, quad = lane >> 4;
  const int r0 = n0 * 25 + blockIdx.x * 128;
  const int rbase = wave * 32;
  bf16_t* hgw = hg + wave * 32 * HGPAD;

  // staging source offsets (bf16 elems): LDS byte p gets source byte
  // row*stride + ((p%stride) ^ ((row&7)<<4))  -> linear-dest swizzled content
  int soff1[4], soff2[4];
  #pragma unroll
  for (int i = 0; i < 4; ++i) {
    int p = wave * 4096 + i * 1024 + lane * 16;
    int row1 = p >> 8;                         // w1: 64 rows x 256 B
    soff1[i] = (row1 * 256 + ((p & 255) ^ ((row1 & 7) << 4))) >> 1;
    int row2 = p >> 7;                         // w2: 128 rows x 128 B
    soff2[i] = (row2 * 128 + ((p & 127) ^ ((row2 & 7) << 4))) >> 1;
  }
  const int swz = (l15 & 7) << 4;              // read-side XOR (row&7 == l15&7)
  int colswz[4];
  #pragma unroll
  for (int ks = 0; ks < 4; ++ks) colswz[ks] = (ks * 64 + quad * 16) ^ swz;

  // per-lane row metadata + x panel into registers
  int nloc[2], lidx[2];
  f32x4 rw[2];
  bf16x8 xf[2][4];
  #pragma unroll
  for (int tc = 0; tc < 2; ++tc) {
    int r = r0 + rbase + tc * 16 + l15;
    int n = r / 25;
    int m = r - n * 25;
    nloc[tc] = n - n0;
    lidx[tc] = (m == 0) ? 0 : (m < 4) ? 1 : (m < 9) ? 2 : (m < 16) ? 3 : 4;
    rw[tc] = *(const f32x4*)&wroute[n * 4];
    const float* xr = x + (size_t)r * CCH + quad * 8;
    #pragma unroll
    for (int ks = 0; ks < 4; ++ks) {
      f32x4 a = *(const f32x4*)(xr + ks * 32);
      f32x4 b = *(const f32x4*)(xr + ks * 32 + 4);
      bf16x8 v;
      #pragma unroll
      for (int q = 0; q < 4; ++q) { v[q] = (bf16_t)a[q]; v[4 + q] = (bf16_t)b[q]; }
      xf[tc][ks] = v;
    }
  }

  f32x4 oacc[8][2];
  #pragma unroll
  for (int i = 0; i < 8; ++i)
    #pragma unroll
    for (int j = 0; j < 2; ++j) oacc[i][j] = {0.f, 0.f, 0.f, 0.f};

  #pragma unroll 1
  for (int e = 0; e < 4; ++e) {
    const bool is_eq = (e < 2);
    #pragma unroll 1
    for (int hc = 0; hc < 8; ++hc) {
      // ---- stage weight chunks (each wave stages its own 4 KB of each) ----
      const bf16_t* g1 = w1T + (size_t)(((e << 3) + hc) << 13);
      const bf16_t* g2 = w2c + (size_t)(((e << 3) + hc) << 13);
      #pragma unroll
      for (int i = 0; i < 4; ++i) {
        GLOAD_LDS(g1 + soff1[i], ws1 + wave * 2048 + i * 512);
        GLOAD_LDS(g2 + soff2[i], ws2 + wave * 2048 + i * 512);
      }
      __syncthreads();   // drains vmcnt(0): staging visible; prev-iter reads done

      // ---- prefetch gates for this (e,hc) into regs (hide L2 under GEMM1) ----
      bf16x4 gv[2][4];
      #pragma unroll
      for (int tc = 0; tc < 2; ++tc) {
        size_t gbase = (size_t)nloc[tc] * GCOLS + hc * 64
                     + (is_eq ? (size_t)(e * 2560 + lidx[tc] * 512)
                              : (size_t)(5120 + (e - 2) * 512));
        #pragma unroll
        for (int tr = 0; tr < 4; ++tr)
          gv[tc][tr] = *(const bf16x4*)&gates[gbase + tr * 16 + quad * 4];
      }

      // ---- GEMM1: hacc[h(4x16)][r(2x16)], K=128, A from ws1 ----
      f32x4 hacc[4][2];
      #pragma unroll
      for (int i = 0; i < 4; ++i)
        #pragma unroll
        for (int j = 0; j < 2; ++j) hacc[i][j] = {0.f, 0.f, 0.f, 0.f};
      #pragma unroll
      for (int ks = 0; ks < 4; ++ks) {
        bf16x8 af[4];
        #pragma unroll
        for (int tr = 0; tr < 4; ++tr)
          af[tr] = *(const bf16x8*)((const char*)ws1 + (l15 + tr * 16) * 256 + colswz[ks]);
        #pragma unroll
        for (int tr = 0; tr < 4; ++tr)
          #pragma unroll
          for (int tc = 0; tc < 2; ++tc)
            hacc[tr][tc] = __builtin_amdgcn_mfma_f32_16x16x32_bf16(af[tr], xf[tc][ks], hacc[tr][tc], 0, 0, 0);
      }
      // ---- gating + hg write (own slice only) ----
      #pragma unroll
      for (int tc = 0; tc < 2; ++tc) {
        float wre = rw[tc][e];
        #pragma unroll
        for (int tr = 0; tr < 4; ++tr) {
          int hl = tr * 16 + quad * 4;
          f32x4 v = hacc[tr][tc];
          bf16x4 g = gv[tc][tr];
          if (is_eq) {
            if (lidx[tc] == 0) {
              #pragma unroll
              for (int q = 0; q < 4; ++q) v[q] = siluf(v[q]);
            }
          } else {
            f32x4 b1 = *(const f32x4*)&ne_b1[(e - 2) * 512 + hc * 64 + hl];
            #pragma unroll
            for (int q = 0; q < 4; ++q) v[q] = siluf(v[q] + b1[q]);
          }
          bf16x4 hv;
          #pragma unroll
          for (int q = 0; q < 4; ++q) hv[q] = (bf16_t)(v[q] * (float)g[q] * wre);
          *(bf16x4*)&hgw[(tc * 16 + l15) * HGPAD + hl] = hv;
        }
      }
      __builtin_amdgcn_wave_barrier();   // intra-wave hg write -> read order
      // ---- GEMM2: oacc[c(8x16)][r(2x16)] += ws2 * hg, K=64 ----
      #pragma unroll
      for (int ks = 0; ks < 2; ++ks) {
        bf16x8 bfr[2];
        #pragma unroll
        for (int tc = 0; tc < 2; ++tc)
          bfr[tc] = *(const bf16x8*)&hgw[(tc * 16 + l15) * HGPAD + ks * 32 + quad * 8];
        #pragma unroll
        for (int tr = 0; tr < 8; ++tr) {
          bf16x8 af2 = *(const bf16x8*)((const char*)ws2 + (l15 + tr * 16) * 128 + colswz[ks]);
          #pragma unroll
          for (int tc = 0; tc < 2; ++tc)
            oacc[tr][tc] = __builtin_amdgcn_mfma_f32_16x16x32_bf16(af2, bfr[tc], oacc[tr][tc], 0, 0, 0);
        }
      }
      __syncthreads();   // all reads of ws1/ws2 done before next stage overwrites
    }
  }
  // ---- epilogue: out[r][c] = oacc + w_ne*b2 terms (fp32 store) ----
  #pragma unroll
  for (int tc = 0; tc < 2; ++tc) {
    size_t rg = (size_t)(r0 + rbase + tc * 16 + l15);
    float wn0 = rw[tc][2], wn1 = rw[tc][3];
    #pragma unroll
    for (int tr = 0; tr < 8; ++tr) {
      int c0 = tr * 16 + quad * 4;
      f32x4 v = oacc[tr][tc];
      f32x4 b20 = *(const f32x4*)&ne_b2[c0];
      f32x4 b21 = *(const f32x4*)&ne_b2[128 + c0];
      f32x4 ov;
      #pragma unroll
      for (int q = 0; q < 4; ++q)
        ov[q] = v[q] + wn0 * b20[q] + wn1 * b21[q];
      *(f32x4*)&out[rg * CCH + c0] = ov;
    }
  }
}

// ---------------- launch ----------------
extern "C" void kernel_launch(void* const* d_in, const int* in_sizes, int n_in,
                              void* d_out, int out_size, void* d_ws, size_t ws_size,
                              hipStream_t stream)
{
  const float* x_emb     = (const float*)d_in[0];
  const float* t_ij      = (const float*)d_in[1];
  const int*   edge_index= (const int*)d_in[2];
  const float* eq_w1     = (const float*)d_in[3];
  const float* eq_gate_w = (const float*)d_in[4];
  const float* eq_gate_b = (const float*)d_in[5];
  const float* eq_w2     = (const float*)d_in[6];
  const float* ne_w1     = (const float*)d_in[7];
  const float* ne_b1     = (const float*)d_in[8];
  const float* ne_gate_w = (const float*)d_in[9];
  const float* ne_gate_b = (const float*)d_in[10];
  const float* ne_w2     = (const float*)d_in[11];
  const float* ne_b2     = (const float*)d_in[12];
  const float* r_w1      = (const float*)d_in[13];
  const float* r_b1      = (const float*)d_in[14];
  const float* r_w2      = (const float*)d_in[15];
  const float* r_b2      = (const float*)d_in[16];
  float* out = (float*)d_out;

  char* ws = (char*)d_ws;
  float*  csum   = (float*)(ws + OFF_CSUM);
  int*    deg    = (int*)(ws + OFF_DEG);
  int*    offs   = (int*)(ws + OFF_OFFS);
  int*    cur    = (int*)(ws + OFF_CUR);
  int*    eids   = (int*)(ws + OFF_EIDS);
  float*  wroute = (float*)(ws + OFF_WRT);
  bf16_t* cbf    = (bf16_t*)(ws + OFF_CBF);
  bf16_t* WpackT = (bf16_t*)(ws + OFF_WPT);
  float*  bpack  = (float*)(ws + OFF_BPK);
  bf16_t* w1T    = (bf16_t*)(ws + OFF_W1T);
  bf16_t* w2c    = (bf16_t*)(ws + OFF_W2T);
  bf16_t* gates  = (bf16_t*)(ws + OFF_GATES);

  // Adaptive node-chunking for the gates buffer (ws_size constant across calls).
  size_t avail = (ws_size > OFF_GATES) ? ws_size - OFF_GATES : 0;
  int chunk = 128;
  for (int c = NNODES; c >= 128; c >>= 1) {
    if ((size_t)c * GCOLS * sizeof(bf16_t) <= avail) { chunk = c; break; }
  }

  hipMemsetAsync(ws + OFF_DEG, 0, 32768, stream);   // zero deg only

  // CSR build + gather-mean
  edge_count_kernel<<<NEDGES / 256, 256, 0, stream>>>(edge_index, deg);
  scan_kernel<<<1, 256, 0, stream>>>(deg, offs, cur);
  edge_fill_kernel<<<NEDGES / 256, 256, 0, stream>>>(edge_index, cur, eids);
  gather_mean_kernel<<<NNODES, 128, 0, stream>>>(t_ij, offs, eids, csum, cbf);

  pack_kernel<<<5144, 256, 0, stream>>>(eq_gate_w, ne_gate_w, eq_gate_b, ne_gate_b,
                                        eq_w1, ne_w1, eq_w2, ne_w2,
                                        WpackT, bpack, w1T, w2c);
  router_kernel<<<NNODES, 128, 0, stream>>>(csum, r_w1, r_b1, r_w2, r_b2, wroute);

  for (int n0 = 0; n0 < NNODES; n0 += chunk) {
    gate_gemm_kernel<<<dim3(GCOLS / 128, chunk / 128), 256, 0, stream>>>(
        WpackT, cbf, bpack, gates, n0);
    fused_experts_kernel<<<chunk * 25 / 128, 256, 0, stream>>>(
        x_emb, w1T, w2c, gates, wroute, ne_b1, ne_b2, out, n0);
  }
}